// Round 4
// baseline (272.927 us; speedup 1.0000x reference)
//
#include <hip/hip_runtime.h>
#include <math.h>

#define NZ    128
#define H1    512
#define H2    1024
#define IMG   784
#define IMGP  832
#define BATCH 4096
#define NGEN  10

typedef _Float16 f16;
typedef __attribute__((ext_vector_type(8))) _Float16 half8;
typedef __attribute__((ext_vector_type(4))) float floatx4;

// ---------------- bucket samples by generator ----------------
__global__ void bucket_kernel(const int* __restrict__ g_idx,
                              int* __restrict__ counts,
                              int* __restrict__ lists) {
    int b = blockIdx.x * blockDim.x + threadIdx.x;
    if (b < BATCH) {
        int g = g_idx[b];
        int pos = atomicAdd(&counts[g], 1);
        lists[g * BATCH + pos] = b;
    }
}

// ---------------- f32 -> f16 convert (z) ----------------
__global__ void conv_f16(const float* __restrict__ x, f16* __restrict__ y, int n) {
    int i = blockIdx.x * 256 + threadIdx.x;
    if (i < n) y[i] = (f16)x[i];
}

// ---------------- transpose W: [g][K][N] f32 -> [g][NPAD][K] f16 ----------------
template<int K, int N, int NPAD>
__global__ __launch_bounds__(256)
void transpose_f16(const float* __restrict__ W, f16* __restrict__ Wt) {
    const int g  = blockIdx.z;
    const int k0 = blockIdx.x * 32;
    const int n0 = blockIdx.y * 32;
    __shared__ f16 L[32][36];
    const int t = threadIdx.x;
    {
        const int kk = t >> 3;
        const int nq = (t & 7) * 4;
        float4 v = make_float4(0.f, 0.f, 0.f, 0.f);
        if (n0 + nq < N)   // N % 4 == 0: quads never straddle
            v = *(const float4*)(W + ((size_t)g * K + (k0 + kk)) * N + n0 + nq);
        L[nq + 0][kk] = (f16)v.x;
        L[nq + 1][kk] = (f16)v.y;
        L[nq + 2][kk] = (f16)v.z;
        L[nq + 3][kk] = (f16)v.w;
    }
    __syncthreads();
    {
        const int nn = t >> 3;
        const int kq = (t & 7) * 4;
        *(ushort4*)(Wt + ((size_t)g * NPAD + (n0 + nn)) * K + k0 + kq) =
            *(const ushort4*)&L[nn][kq];
    }
}

// ---------------- weight-stationary grouped GEMM ----------------
// Block = (m-slice, n-tile, K-slice, generator). B-slice [NT][KLEN] in LDS;
// no barrier in the hot loop: waves stream MFMA A-fragments from global.
// Each wave owns exactly one 32-row supertile (MT=2 m-frags), MSPLIT chosen
// so m_len/32 ~= 4 (one supertile per wave, balanced).
// MODE: 0 = relu->f16, 1 = tanh->f32, 2 = raw f32 partial (K-split)
template<int KLEN, int KSTRIDE, int NOUT, int NPADB, int NT, int NTILES,
         int MT, int MSPLIT, int MODE>
__global__ __launch_bounds__(256, 4)
void gemm_ws(const f16* __restrict__ A, const f16* __restrict__ Wt,
             const float* __restrict__ bias,
             f16* __restrict__ Ch, float* __restrict__ Cf,
             const int* __restrict__ counts, const int* __restrict__ lists) {
    constexpr int KP = KLEN + 8;     // row pad: bank-quad shift of 4/row
    constexpr int NF = NT / 16;
    const int g  = blockIdx.z;
    const int ng = counts[g];
    if (ng <= 0) return;
    const int ks   = blockIdx.y / NTILES;
    const int n0   = (blockIdx.y % NTILES) * NT;
    const int koff = ks * KLEN;
    const int m_start = (int)(((long long)blockIdx.x * ng) / MSPLIT);
    const int m_end   = (int)(((long long)(blockIdx.x + 1) * ng) / MSPLIT);
    const int m_len   = m_end - m_start;
    if (m_len <= 0) return;          // block-uniform

    __shared__ f16 Bs[NT * KP];
    const int tid = threadIdx.x;

    #pragma unroll
    for (int i = tid; i < NT * (KLEN / 8); i += 256) {
        const int row = i / (KLEN / 8);
        const int kq  = (i % (KLEN / 8)) * 8;
        *(half8*)&Bs[row * KP + kq] =
            *(const half8*)(Wt + ((size_t)g * NPADB + n0 + row) * KSTRIDE + koff + kq);
    }
    __syncthreads();

    const int lane = tid & 63, w = tid >> 6;
    const int lm = lane & 15, lq = lane >> 4;

    float bs[NF];
    if (MODE < 2) {
        #pragma unroll
        for (int nf = 0; nf < NF; ++nf) {
            const int n = n0 + nf * 16 + lm;
            bs[nf] = (n < NOUT) ? bias[(size_t)g * NOUT + n] : 0.f;
        }
    }

    const int* lst = lists + g * BATCH;
    float* dstp = (MODE == 2) ? (Cf + (size_t)ks * BATCH * NOUT) : Cf;

    for (int st = w; st * (MT * 16) < m_len; st += 4) {
        const int m0 = m_start + st * MT * 16;
        const f16* ap[MT];
        #pragma unroll
        for (int mt = 0; mt < MT; ++mt) {
            const int r = m0 + mt * 16 + lm;
            const int s = lst[min(r, ng - 1)];
            ap[mt] = A + (size_t)s * KSTRIDE + koff + lq * 8;
        }

        floatx4 acc[MT][NF] = {};
        #pragma unroll
        for (int kc = 0; kc < KLEN / 32; ++kc) {
            half8 bb[NF];
            #pragma unroll
            for (int nf = 0; nf < NF; ++nf)
                bb[nf] = *(const half8*)&Bs[(nf * 16 + lm) * KP + kc * 32 + lq * 8];
            #pragma unroll
            for (int mt = 0; mt < MT; ++mt) {
                const half8 ah = *(const half8*)(ap[mt] + kc * 32);
                #pragma unroll
                for (int nf = 0; nf < NF; ++nf)
                    acc[mt][nf] = __builtin_amdgcn_mfma_f32_16x16x32_f16(
                        ah, bb[nf], acc[mt][nf], 0, 0, 0);
            }
        }

        // epilogue: C/D layout col = lane&15, row = (lane>>4)*4 + reg
        #pragma unroll
        for (int mt = 0; mt < MT; ++mt)
            #pragma unroll
            for (int rr = 0; rr < 4; ++rr) {
                const int row = m0 + mt * 16 + lq * 4 + rr;
                if (row >= m_end) continue;
                const int s = lst[row];
                #pragma unroll
                for (int nf = 0; nf < NF; ++nf) {
                    const int n = n0 + nf * 16 + lm;
                    if (n >= NOUT) continue;
                    float x = acc[mt][nf][rr];
                    if (MODE == 0) {
                        Ch[(size_t)s * NOUT + n] = (f16)fmaxf(x + bs[nf], 0.f);
                    } else if (MODE == 1) {
                        const float e = __expf(2.f * (x + bs[nf]));
                        Cf[(size_t)s * NOUT + n] = 1.f - 2.f / (e + 1.f);
                    } else {
                        dstp[(size_t)s * NOUT + n] = x;
                    }
                }
            }
    }
}

// ---------------- combine K-split partials: tanh(p0+p1+bias) ----------------
__global__ __launch_bounds__(256)
void combine_tanh(const float* __restrict__ p, const float* __restrict__ bias,
                  const int* __restrict__ g_idx, float* __restrict__ out) {
    const int i = blockIdx.x * 256 + threadIdx.x;   // over BATCH*(IMG/4)
    const int s  = i / (IMG / 4);
    const int nq = (i % (IMG / 4)) * 4;
    const int g  = g_idx[s];
    float4 a = *(const float4*)(p + (size_t)s * IMG + nq);
    float4 b = *(const float4*)(p + (size_t)BATCH * IMG + (size_t)s * IMG + nq);
    float4 c = *(const float4*)(bias + (size_t)g * IMG + nq);
    float4 r;
    float* rp = (float*)&r;
    const float xs[4] = {a.x + b.x + c.x, a.y + b.y + c.y,
                         a.z + b.z + c.z, a.w + b.w + c.w};
    #pragma unroll
    for (int j = 0; j < 4; ++j) {
        const float e = __expf(2.f * xs[j]);
        rp[j] = 1.f - 2.f / (e + 1.f);
    }
    *(float4*)(out + (size_t)s * IMG + nq) = r;
}

extern "C" void kernel_launch(void* const* d_in, const int* in_sizes, int n_in,
                              void* d_out, int out_size, void* d_ws, size_t ws_size,
                              hipStream_t stream) {
    const float* z    = (const float*)d_in[0];
    const int*   gidx = (const int*)  d_in[1];
    const float* W1   = (const float*)d_in[2];
    const float* b1   = (const float*)d_in[3];
    const float* W2   = (const float*)d_in[4];
    const float* b2   = (const float*)d_in[5];
    const float* W3   = (const float*)d_in[6];
    const float* b3   = (const float*)d_in[7];
    float* out = (float*)d_out;

    char* ws = (char*)d_ws;
    size_t off = 0;
    auto alloc = [&](size_t bytes) { size_t o = off; off = (off + bytes + 255) & ~255ULL; return o; };
    int* counts = (int*)(ws + alloc(256));
    int* lists  = (int*)(ws + alloc((size_t)BATCH * NGEN * 4));
    f16* zh  = (f16*)(ws + alloc((size_t)BATCH * NZ * 2));
    f16* h1  = (f16*)(ws + alloc((size_t)BATCH * H1 * 2));
    f16* h2  = (f16*)(ws + alloc((size_t)BATCH * H2 * 2));
    f16* W1t = (f16*)(ws + alloc((size_t)NGEN * H1 * NZ * 2));
    f16* W2t = (f16*)(ws + alloc((size_t)NGEN * H2 * H1 * 2));
    f16* W3t = (f16*)(ws + alloc((size_t)NGEN * IMGP * H2 * 2));
    float* p = (float*)(ws + alloc((size_t)2 * BATCH * IMG * 4));

    hipMemsetAsync(counts, 0, 256, stream);
    bucket_kernel<<<dim3(BATCH / 256), dim3(256), 0, stream>>>(gidx, counts, lists);
    conv_f16<<<dim3((BATCH * NZ) / 256), dim3(256), 0, stream>>>(z, zh, BATCH * NZ);
    transpose_f16<NZ, H1, H1><<<dim3(NZ / 32, H1 / 32, NGEN), dim3(256), 0, stream>>>(W1, W1t);
    transpose_f16<H1, H2, H2><<<dim3(H1 / 32, H2 / 32, NGEN), dim3(256), 0, stream>>>(W2, W2t);
    transpose_f16<H2, IMG, IMGP><<<dim3(H2 / 32, IMGP / 32, NGEN), dim3(256), 0, stream>>>(W3, W3t);

    // L1: K=128, LDS 8.7 KB, grid 640 blocks
    gemm_ws<NZ, NZ, H1, H1, 32, H1 / 32, 2, 4, 0>
        <<<dim3(4, H1 / 32, NGEN), dim3(256), 0, stream>>>(
            zh, W1t, b1, h1, nullptr, counts, lists);
    // L2: K=512, LDS 33 KB, grid 1280 blocks
    gemm_ws<H1, H1, H2, H2, 32, H2 / 32, 2, 4, 0>
        <<<dim3(4, H2 / 32, NGEN), dim3(256), 0, stream>>>(
            h1, W2t, b2, h2, nullptr, counts, lists);
    // L3: K=1024 split into 2x512, LDS 33 KB, grid 2080 blocks, raw partials
    gemm_ws<512, H2, IMG, IMGP, 32, IMGP / 32, 2, 4, 2>
        <<<dim3(4, 2 * (IMGP / 32), NGEN), dim3(256), 0, stream>>>(
            h2, W3t, nullptr, nullptr, p, counts, lists);
    // combine: tanh(p0+p1+bias) -> out
    combine_tanh<<<dim3(BATCH * (IMG / 4) / 256), dim3(256), 0, stream>>>(
        p, b3, gidx, out);
}